// Round 8
// baseline (143.847 us; speedup 1.0000x reference)
//
#include <hip/hip_runtime.h>
#include <hip/hip_bf16.h>

using short8  = __attribute__((ext_vector_type(8))) short;
using floatx4 = __attribute__((ext_vector_type(4))) float;

// ---------------------------------------------------------------------------
// prepack: weights fp32 -> bf16 in MFMA-B-fragment-tiled layout (unchanged).
// Fragment (nblk, kstep) = 64 lanes x 8 elems contiguous (1 KiB); lane l holds
// B[n = nblk*16 + (l&15)][k = kstep*32 + (l>>4)*8 .. +7].
//  wsb_t: from w_sample [256 s][1024 k]  -> frag idx = nblk*32 + kstep  (16x32)
//  wib_t: from w_init  [1024 k'][256 s]  -> frag idx = nblk*8  + kstep  (64x8)
// ---------------------------------------------------------------------------
__global__ __launch_bounds__(256) void prepack_kernel(const float* __restrict__ w_sample,
                                                      const float* __restrict__ w_init,
                                                      __hip_bfloat16* __restrict__ wsb_t,
                                                      __hip_bfloat16* __restrict__ wib_t) {
    const int tg   = blockIdx.x * 256 + threadIdx.x;   // 0..65535
    const int lane = tg & 63;
    const int l16  = lane & 15, quad = lane >> 4;
    const float* src;
    __hip_bfloat16* dst;
    if (tg < 32768) {
        const int chunk = tg >> 6;                     // 0..511: nblk=chunk>>5, kstep=chunk&31
        const int n = (chunk >> 5) * 16 + l16;
        const int k = (chunk & 31) * 32 + quad * 8;
        src = w_sample + (size_t)n * 1024 + k;
        dst = wsb_t + (size_t)tg * 8;
    } else {
        const int t2 = tg - 32768;
        const int chunk = t2 >> 6;                     // 0..511: nblk=chunk>>3, kstep=chunk&7
        const int n = (chunk >> 3) * 16 + l16;
        const int k = (chunk & 7) * 32 + quad * 8;
        src = w_init + (size_t)n * 256 + k;
        dst = wib_t + (size_t)t2 * 8;
    }
    floatx4 v0 = *(const floatx4*)(src);
    floatx4 v1 = *(const floatx4*)(src + 4);
    union { short8 s; __hip_bfloat16 h[8]; } u;
#pragma unroll
    for (int i = 0; i < 4; ++i) {
        u.h[i]     = __float2bfloat16(v0[i]);
        u.h[4 + i] = __float2bfloat16(v1[i]);
    }
    *(short8*)dst = u.s;
}

// ---------------------------------------------------------------------------
// fused v8: MERGED phases, M=64 patches/block (2 nh-slabs), grid 256 =
// exactly 1 block/CU, 1024 thr = 16 waves = 4 waves/SIMD.
// Rationale (r7 post-mortem): split kernels were ~53 us combined; the two
// dominant structural costs were (a) 2x512 MB weight L2 broadcast (512
// blocks x 1 MB), (b) meas HBM round-trip. M=64 halves (a); merging kills
// (b). Both K-streams remain barrier-free; 3 barriers total.
// LDS: As = 128 KB (64 patches x 1024 k bf16, XOR-swizzled byte =
// linear ^ ((p&7)<<4), same involution both sides -- r7-verified). Ms
// (64 x 264 bf16 = 33 KB) aliases the dead As region after phase 1.
//  Phase 1: meas[64x256] = patch[64x1024] @ Ws^T; 16 waves as 2M x 8N,
//   wave tile 32x32 (acc[2][2]); per ks: 2 ds_read_b128 + 2 L2 frag loads
//   + 4 MFMA, 32 ks, no barriers.
//  Phase 2: rec[64x1024] = meas @ Wi^T; 16 waves as 2M x 8N, wave tile
//   32x128 in 2 chunks of 64 (acc[2][4], r0-proven shape); fold-epilogue
//   per chunk (stores of chunk 0 overlap compute of chunk 1).
// Verified layouts: A/B frag row=lane&15, k=quad*8+j; C/D col=lane&15,
// row=quad*4+reg.
// ---------------------------------------------------------------------------
__global__ __launch_bounds__(1024, 1) void fused_kernel(const float* __restrict__ x,
                                                        const __hip_bfloat16* __restrict__ wsb_t,
                                                        const __hip_bfloat16* __restrict__ wib_t,
                                                        float* __restrict__ Y) {
    __shared__ __align__(16) char smem[131072];        // As 128 KB; Ms aliased
    __hip_bfloat16* As = (__hip_bfloat16*)smem;
    __hip_bfloat16* Ms = (__hip_bfloat16*)smem;        // alias (As dead by then)

    const int tid  = threadIdx.x;
    const int wave = tid >> 6, lane = tid & 63;
    const int quad = lane >> 4, l16 = lane & 15;
    const int wm   = wave >> 3, wn = wave & 7;         // 2M x 8N wave grid
    const int blk  = blockIdx.x;                       // slab pair: slabs 2blk, 2blk+1

    // ---- stage x (256 KB fp32 -> 128 KB bf16 LDS), one shot ----
    // thread t: image row rl = t>>4 (0..63), cols (t&15)*64 .. +64
    //  -> patches p = (rl>>5)*32 + (t&15)*2 + seg, in-patch row r' = rl&31.
    // As element (p, k = r'*32 + kw) at byte (p*2048 + r'*64 + kw*2) ^ ((p&7)<<4).
    {
        const float* src = x + (size_t)blk * 65536 + (size_t)(tid >> 4) * 1024 + (tid & 15) * 64;
        const int rl = tid >> 4;
        const int pb = (rl >> 5) * 32 + (tid & 15) * 2;
        const int rp = rl & 31;
#pragma unroll
        for (int seg = 0; seg < 2; ++seg) {
            const float* s = src + seg * 32;
            const int p   = pb + seg;
            const int lin = p * 2048 + rp * 64;
            const int xm  = (p & 7) << 4;
#pragma unroll
            for (int i = 0; i < 4; ++i) {
                floatx4 a = *(const floatx4*)(s + i * 8);
                floatx4 b = *(const floatx4*)(s + i * 8 + 4);
                union { short8 v; __hip_bfloat16 h[8]; } u;
#pragma unroll
                for (int q = 0; q < 4; ++q) {
                    u.h[q]     = __float2bfloat16(a[q]);
                    u.h[4 + q] = __float2bfloat16(b[q]);
                }
                *(short8*)(smem + ((lin + i * 16) ^ xm)) = u.v;
            }
        }
    }
    __syncthreads();                                   // barrier 1: As ready

    // ---- phase 1 K-stream (barrier-free): wave (wm,wn) -> m [wm*32,+32),
    //      s [wn*32,+32); nblk = wn*2 + j ----
    floatx4 acc[2][2];
#pragma unroll
    for (int i = 0; i < 2; ++i)
#pragma unroll
        for (int j = 0; j < 2; ++j) acc[i][j] = {0.f, 0.f, 0.f, 0.f};
    {
        const __hip_bfloat16* bw = wsb_t + (size_t)wn * 32768 + (size_t)lane * 8;
#pragma unroll 8
        for (int ks = 0; ks < 32; ++ks) {
            short8 af[2], bfr[2];
#pragma unroll
            for (int i = 0; i < 2; ++i) {
                const int row  = wm * 32 + i * 16 + l16;
                const int boff = (row * 2048 + ks * 64 + quad * 16) ^ ((row & 7) << 4);
                af[i] = *(const short8*)(smem + boff);
            }
#pragma unroll
            for (int j = 0; j < 2; ++j)
                bfr[j] = *(const short8*)(bw + (size_t)j * 16384 + (size_t)ks * 512);
#pragma unroll
            for (int i = 0; i < 2; ++i)
#pragma unroll
                for (int j = 0; j < 2; ++j)
                    acc[i][j] = __builtin_amdgcn_mfma_f32_16x16x32_bf16(af[i], bfr[j], acc[i][j], 0, 0, 0);
        }
    }
    __syncthreads();                                   // barrier 2: As reads done (alias safety)

    // ---- meas (bf16, same rounding as r0) -> Ms [64][264] ----
#pragma unroll
    for (int i = 0; i < 2; ++i)
#pragma unroll
        for (int j = 0; j < 2; ++j)
#pragma unroll
            for (int r = 0; r < 4; ++r) {
                const int row = wm * 32 + i * 16 + quad * 4 + r;
                const int col = wn * 32 + j * 16 + l16;
                Ms[row * 264 + col] = __float2bfloat16(acc[i][j][r]);
            }
    __syncthreads();                                   // barrier 3: Ms ready

    // ---- phase 2 K-stream (barrier-free): wave (wm,wn) -> m [wm*32,+32),
    //      n [wn*128,+128) as 2 chunks of 64; nblk' = wn*8 + c*4 + j ----
    float* yb = Y + (size_t)blk * 65536;
    const __hip_bfloat16* bw2 = wib_t + (size_t)wn * 32768 + (size_t)lane * 8;
#pragma unroll 1
    for (int c = 0; c < 2; ++c) {
        floatx4 a2[2][4];
#pragma unroll
        for (int i = 0; i < 2; ++i)
#pragma unroll
            for (int j = 0; j < 4; ++j) a2[i][j] = {0.f, 0.f, 0.f, 0.f};
        const __hip_bfloat16* w2 = bw2 + (size_t)c * 16384;
#pragma unroll
        for (int ks = 0; ks < 8; ++ks) {
            short8 af[2], bfr[4];
#pragma unroll
            for (int i = 0; i < 2; ++i)
                af[i] = *(const short8*)&Ms[(wm * 32 + i * 16 + l16) * 264 + ks * 32 + quad * 8];
#pragma unroll
            for (int j = 0; j < 4; ++j)
                bfr[j] = *(const short8*)(w2 + (size_t)j * 4096 + (size_t)ks * 512);
#pragma unroll
            for (int i = 0; i < 2; ++i)
#pragma unroll
                for (int j = 0; j < 4; ++j)
                    a2[i][j] = __builtin_amdgcn_mfma_f32_16x16x32_bf16(af[i], bfr[j], a2[i][j], 0, 0, 0);
        }
        // fold epilogue: p = wm*32 + i*16 + quad*4 + r;
        // col = wn*128 + c*64 + j*16 + l16 -> (kh = col>>5, kw = col&31);
        // y[slab = p>>5][kh*1024 + (p&31)*32 + kw]
#pragma unroll
        for (int i = 0; i < 2; ++i)
#pragma unroll
            for (int r = 0; r < 4; ++r) {
                const int p = wm * 32 + i * 16 + quad * 4 + r;
                float* yp = yb + (size_t)(p >> 5) * 32768 + (p & 31) * 32;
#pragma unroll
                for (int j = 0; j < 4; ++j) {
                    const int col = wn * 128 + c * 64 + j * 16 + l16;
                    yp[(col >> 5) * 1024 + (col & 31)] = a2[i][j][r];
                }
            }
    }
}

// ---------------------------------------------------------------------------
// Workspace: wsb_t bf16 [262144] @ 0; wib_t bf16 [262144] @ 524288. 1 MB.
// 2 dispatches.
// ---------------------------------------------------------------------------
extern "C" void kernel_launch(void* const* d_in, const int* in_sizes, int n_in,
                              void* d_out, int out_size, void* d_ws, size_t ws_size,
                              hipStream_t stream) {
    const float* x        = (const float*)d_in[0];
    const float* w_sample = (const float*)d_in[1];
    const float* w_init   = (const float*)d_in[2];
    float* y = (float*)d_out;
    char* ws = (char*)d_ws;

    __hip_bfloat16* wsb_t = (__hip_bfloat16*)(ws);
    __hip_bfloat16* wib_t = (__hip_bfloat16*)(ws + (size_t)524288);

    prepack_kernel<<<256, 256, 0, stream>>>(w_sample, w_init, wsb_t, wib_t);
    fused_kernel<<<256, 1024, 0, stream>>>(x, wsb_t, wib_t, y);
}